// Round 6
// baseline (613.072 us; speedup 1.0000x reference)
//
#include <hip/hip_runtime.h>

#define N_IN 512
#define HID 64
#define NBLK 256   // edge-chunk blocks for hist/partition passes
#define TILE 2048  // partB LDS sort tile

typedef __attribute__((ext_vector_type(4))) float f32x4;
typedef __attribute__((ext_vector_type(8))) short bf16x8;

__device__ inline float bf2f(unsigned short s) {
    union { unsigned int u; float f; } v; v.u = ((unsigned int)s) << 16; return v.f;
}
__device__ inline unsigned short f2bf(float f) {
    union { float f; unsigned int u; } v; v.f = f;
    unsigned int u = v.u;
    return (unsigned short)((u + 0x7FFFu + ((u >> 16) & 1u)) >> 16);
}

// ---- pass A: per-(bucket, block) histogram (LDS atomics) + W1 transpose ----
__global__ __launch_bounds__(256) void k_histA_wt(const int* __restrict__ EI, int* __restrict__ hist,
                                                  const float* __restrict__ W1, unsigned short* __restrict__ Wt,
                                                  int E, int N, int K) {
    if (blockIdx.x >= NBLK) {   // W1 [512][64] fp32 -> Wt [64][512] bf16
        int i = (blockIdx.x - NBLK) * 256 + threadIdx.x;
        int k = i >> 6, n = i & 63;
        Wt[n * 512 + k] = f2bf(W1[i]);
        return;
    }
    __shared__ int hs[512];
    __shared__ int sflag;
    if (threadIdx.x == 0) sflag = (EI[1] == 0 && EI[3] == 0 && EI[5] == 0 && EI[7] == 0) ? 1 : 0;
    for (int k = threadIdx.x; k < 512; k += 256) hs[k] = 0;
    __syncthreads();
    bool f = sflag != 0;
    int chunk = (E + NBLK - 1) / NBLK;
    int s = blockIdx.x * chunk, e = min(E, s + chunk);
    for (int i = s + threadIdx.x; i < e; i += 256) {
        int c = f ? ((const int2*)EI)[E + i].x : EI[E + i];
        if ((unsigned)c < (unsigned)N) atomicAdd(&hs[c >> 8], 1);
    }
    __syncthreads();
    for (int k = threadIdx.x; k < K; k += 256) hist[k * NBLK + blockIdx.x] = hs[k];
}

// ---- block-local exclusive scan (256-entry blocks; NBLK==256 so 1 block == 1 bucket)
__global__ __launch_bounds__(256) void k_scan_a2(int* __restrict__ data, int* __restrict__ bsum, int n) {
    __shared__ int sd[256];
    int i = blockIdx.x * 256 + threadIdx.x;
    int v = (i < n) ? data[i] : 0;
    sd[threadIdx.x] = v;
    __syncthreads();
    for (int off = 1; off < 256; off <<= 1) {
        int t = 0;
        if (threadIdx.x >= (unsigned)off) t = sd[threadIdx.x - off];
        __syncthreads();
        sd[threadIdx.x] += t;
        __syncthreads();
    }
    if (i < n) data[i] = sd[threadIdx.x] - v;
    if (threadIdx.x == 255) bsum[blockIdx.x] = sd[255];
}

__global__ __launch_bounds__(512) void k_scan_b(const int* __restrict__ bsum, int* __restrict__ bexc, int nb) {
    __shared__ int sd[512];
    int t = threadIdx.x;
    int v = (t < nb) ? bsum[t] : 0;
    sd[t] = v;
    __syncthreads();
    for (int off = 1; off < 512; off <<= 1) {
        int u = 0;
        if (t >= off) u = sd[t - off];
        __syncthreads();
        sd[t] += u;
        __syncthreads();
    }
    if (t < nb) bexc[t] = sd[t] - v;
    if (t == 511) bexc[nb] = sd[511];
}

// ---- pass B v2: LDS counting-sort per tile, coalesced segment writes -------
__global__ __launch_bounds__(256) void k_partB(const int* __restrict__ EI, const int* __restrict__ hist,
                                               const int* __restrict__ bexc, int* __restrict__ edges2,
                                               int E, int N, int K) {
    __shared__ int val[TILE];
    __shared__ unsigned short bkt[TILE];
    __shared__ int sorted[TILE];
    __shared__ unsigned short sbkt[TILE];
    __shared__ int cnt[512], seg[512], cur[512], gcur[512];
    __shared__ int wsum[4];
    __shared__ int sflag;
    int tid = threadIdx.x, b = blockIdx.x;
    int lane = tid & 63, wv = tid >> 6;
    if (tid == 0) sflag = (EI[1] == 0 && EI[3] == 0 && EI[5] == 0 && EI[7] == 0) ? 1 : 0;
    // global cursor for each (bucket k, this block): bexc[k] + block-local prefix
    for (int k = tid; k < 512; k += 256) gcur[k] = (k < K) ? (bexc[k] + hist[k * NBLK + b]) : 0;
    __syncthreads();
    bool f = sflag != 0;
    int chunk = (E + NBLK - 1) / NBLK;
    int s = b * chunk, e = min(E, s + chunk);
    for (int ts = s; ts < e; ts += TILE) {
        int n = min(e - ts, TILE);
        for (int k = tid; k < 512; k += 256) cnt[k] = 0;
        __syncthreads();
        for (int i = tid; i < n; i += 256) {
            int r, c;
            if (f) { const int2* E2 = (const int2*)EI; r = E2[ts + i].x; c = E2[E + ts + i].x; }
            else   { r = EI[ts + i]; c = EI[E + ts + i]; }
            if ((unsigned)c < (unsigned)N) {
                unsigned short kb = (unsigned short)(c >> 8);
                if ((unsigned)r >= (unsigned)N) r = 0;   // clamp (slot must stay occupied)
                val[i] = r | ((c & 255) << 20);
                bkt[i] = kb;
                atomicAdd(&cnt[kb], 1);
            } else bkt[i] = 0xFFFFu;
        }
        __syncthreads();
        // scan cnt[0..511]: thread t owns pair (2t, 2t+1); shfl scan of pair sums
        int v0 = cnt[2 * tid], v1 = cnt[2 * tid + 1];
        int p = v0 + v1, pi = p;
        for (int d = 1; d < 64; d <<= 1) {
            int u = __shfl_up(pi, d, 64);
            if (lane >= d) pi += u;
        }
        if (lane == 63) wsum[wv] = pi;
        __syncthreads();
        int woff = 0, tot = 0;
        for (int q = 0; q < 4; ++q) { int t2 = wsum[q]; if (q < wv) woff += t2; tot += t2; }
        int pe = woff + pi - p;      // exclusive pair prefix
        seg[2 * tid] = pe; seg[2 * tid + 1] = pe + v0;
        cur[2 * tid] = pe; cur[2 * tid + 1] = pe + v0;
        __syncthreads();
        // scatter into sorted LDS tile
        for (int i = tid; i < n; i += 256) {
            unsigned short kb = bkt[i];
            if (kb != 0xFFFFu) {
                int pos = atomicAdd(&cur[kb], 1);
                sorted[pos] = val[i];
                sbkt[pos] = kb;
            }
        }
        __syncthreads();
        // coalesced write-out: consecutive threads -> consecutive global within segment
        for (int j = tid; j < tot; j += 256) {
            int kb = sbkt[j];
            edges2[gcur[kb] + (j - seg[kb])] = sorted[j];
        }
        __syncthreads();
        for (int k = tid; k < K; k += 256) gcur[k] += cnt[k];
        __syncthreads();
    }
}

// ---- GEMM1 (MFMA, no LDS): H[m] = X[m]·W1 bf16 (raw; dinv applied in bucket)
__global__ __launch_bounds__(256) void k_gemm1(const float* __restrict__ X, const unsigned short* __restrict__ Wt,
                                               unsigned short* __restrict__ H, int N) {
    int tid = threadIdx.x;
    int w = tid >> 6, lane = tid & 63;
    int m_l = lane & 15, q = lane >> 4;
    int m0 = blockIdx.x * 128 + w * 32;
    int rA0 = m0 + m_l, rA1 = m0 + 16 + m_l;
    int rc0 = rA0 < N ? rA0 : N - 1;
    int rc1 = rA1 < N ? rA1 : N - 1;
    const float* baseA0 = X + (size_t)rc0 * 512 + q * 8;
    const float* baseA1 = X + (size_t)rc1 * 512 + q * 8;
    const unsigned short* baseB = Wt + (size_t)m_l * 512 + q * 8;

    f32x4 acc[2][4] = {};
#pragma unroll 4
    for (int c = 0; c < 16; ++c) {
        int ko = c * 32;
        float4 x0a = *(const float4*)(baseA0 + ko);
        float4 x0b = *(const float4*)(baseA0 + ko + 4);
        float4 x1a = *(const float4*)(baseA1 + ko);
        float4 x1b = *(const float4*)(baseA1 + ko + 4);
        bf16x8 a0, a1;
        a0[0] = (short)f2bf(x0a.x); a0[1] = (short)f2bf(x0a.y); a0[2] = (short)f2bf(x0a.z); a0[3] = (short)f2bf(x0a.w);
        a0[4] = (short)f2bf(x0b.x); a0[5] = (short)f2bf(x0b.y); a0[6] = (short)f2bf(x0b.z); a0[7] = (short)f2bf(x0b.w);
        a1[0] = (short)f2bf(x1a.x); a1[1] = (short)f2bf(x1a.y); a1[2] = (short)f2bf(x1a.z); a1[3] = (short)f2bf(x1a.w);
        a1[4] = (short)f2bf(x1b.x); a1[5] = (short)f2bf(x1b.y); a1[6] = (short)f2bf(x1b.z); a1[7] = (short)f2bf(x1b.w);
#pragma unroll
        for (int t = 0; t < 4; ++t) {
            bf16x8 bb = *(const bf16x8*)(baseB + (size_t)t * 16 * 512 + ko);
            acc[0][t] = __builtin_amdgcn_mfma_f32_16x16x32_bf16(a0, bb, acc[0][t], 0, 0, 0);
            acc[1][t] = __builtin_amdgcn_mfma_f32_16x16x32_bf16(a1, bb, acc[1][t], 0, 0, 0);
        }
    }
#pragma unroll
    for (int h = 0; h < 2; ++h) {
#pragma unroll
        for (int rg = 0; rg < 4; ++rg) {
            int row = m0 + h * 16 + q * 4 + rg;
            if (row < N) {
#pragma unroll
                for (int t = 0; t < 4; ++t)
                    H[(size_t)row * 64 + t * 16 + m_l] = f2bf(acc[h][t][rg]);
            }
        }
    }
}

// ---- per-bucket: fine CSR (start/dinv + edge scatter) + H prescale --------
__global__ __launch_bounds__(256) void k_bucket(const int* __restrict__ bexc, const int* __restrict__ edges2,
                                                int* __restrict__ edges, int* __restrict__ start,
                                                float* __restrict__ dinv, unsigned short* __restrict__ H,
                                                int N, int K) {
    __shared__ int hist[256], sd[256], cur[256];
    __shared__ float dvs[256];
    int b = blockIdx.x, tid = threadIdx.x;
    int base = bexc[b];
    int end  = bexc[b + 1];
    hist[tid] = 0;
    __syncthreads();
    for (int i = base + tid; i < end; i += 256)
        atomicAdd(&hist[(edges2[i] >> 20) & 255], 1);
    __syncthreads();
    int v = hist[tid];
    sd[tid] = v;
    __syncthreads();
    for (int off = 1; off < 256; off <<= 1) {
        int t = 0;
        if (tid >= off) t = sd[tid - off];
        __syncthreads();
        sd[tid] += t;
        __syncthreads();
    }
    int excl = sd[tid] - v;
    cur[tid] = excl;
    int node = b * 256 + tid;
    float dvv = rsqrtf((float)(v + 1));
    dvs[tid] = dvv;
    if (node < N) {
        start[node] = base + excl;
        dinv[node] = dvv;
    }
    if (b == 0 && tid == 0) start[N] = bexc[K];
    __syncthreads();
    for (int i = base + tid; i < end; i += 256) {
        int pv = edges2[i];
        int pos = atomicAdd(&cur[(pv >> 20) & 255], 1);
        edges[base + pos] = pv & 0xFFFFF;
    }
    // prescale this bucket's H rows by dinv (16 lanes per row, coalesced)
    for (int rr = tid >> 4; rr < 256; rr += 16) {
        int n2 = b * 256 + rr;
        if (n2 < N) {
            float dv2 = dvs[rr];
            uint2* pp = (uint2*)(H + (size_t)n2 * 64 + (size_t)(tid & 15) * 4);
            uint2 vv = *pp;
            float f0 = bf2f((unsigned short)(vv.x & 0xffffu)) * dv2;
            float f1 = bf2f((unsigned short)(vv.x >> 16)) * dv2;
            float f2 = bf2f((unsigned short)(vv.y & 0xffffu)) * dv2;
            float f3 = bf2f((unsigned short)(vv.y >> 16)) * dv2;
            vv.x = (unsigned int)f2bf(f0) | ((unsigned int)f2bf(f1) << 16);
            vv.y = (unsigned int)f2bf(f2) | ((unsigned int)f2bf(f3) << 16);
            *pp = vv;
        }
    }
}

// ---- fused agg1 + gemm2: wave/node; gather -> relu(x1) -> x1·W2 -> bf16 H2
__global__ __launch_bounds__(256) void k_agg1g2(const unsigned short* __restrict__ H, const int* __restrict__ edges,
                                                const int* __restrict__ start, const float* __restrict__ dinv,
                                                const float* __restrict__ b1, const float* __restrict__ W2,
                                                unsigned short* __restrict__ H2, int N) {
    __shared__ float w2s[64 * 17];   // [k][c] stride 17: 2-way bank alias only
    int tid = threadIdx.x;
    for (int i = tid; i < 1024; i += 256) { int k = i >> 4, c = i & 15; w2s[k * 17 + c] = W2[i]; }
    __syncthreads();
    int wid = blockIdx.x * 4 + (tid >> 6);
    int lane = tid & 63;
    if (wid >= N) return;
    int g = lane >> 4;                  // edge slot 0..3
    int c4 = lane & 15;                 // channel group: channels c4*4 .. +3
    const size_t coff = (size_t)c4 * 4;
    float a0 = 0.f, a1 = 0.f, a2 = 0.f, a3 = 0.f;
    int s = start[wid], e = start[wid + 1];
    int i = s;
    if ((i & 3) && i < e) {             // peel to 16B-aligned edge index
        int lim = min(e, (i + 3) & ~3);
        int j = i + g;
        if (j < lim) {
            uint2 v = *(const uint2*)(H + (size_t)edges[j] * 64 + coff);
            a0 += __uint_as_float(v.x << 16);
            a1 += __uint_as_float(v.x & 0xffff0000u);
            a2 += __uint_as_float(v.y << 16);
            a3 += __uint_as_float(v.y & 0xffff0000u);
        }
        i = lim;
    }
    for (; i + 32 <= e; i += 32) {      // 32 edges: 2 idx int4 + 8 gathers in flight
        int4 s0 = *(const int4*)(edges + i + g * 4);
        int4 s1 = *(const int4*)(edges + i + 16 + g * 4);
        uint2 v0 = *(const uint2*)(H + (size_t)s0.x * 64 + coff);
        uint2 v1 = *(const uint2*)(H + (size_t)s0.y * 64 + coff);
        uint2 v2 = *(const uint2*)(H + (size_t)s0.z * 64 + coff);
        uint2 v3 = *(const uint2*)(H + (size_t)s0.w * 64 + coff);
        uint2 v4 = *(const uint2*)(H + (size_t)s1.x * 64 + coff);
        uint2 v5 = *(const uint2*)(H + (size_t)s1.y * 64 + coff);
        uint2 v6 = *(const uint2*)(H + (size_t)s1.z * 64 + coff);
        uint2 v7 = *(const uint2*)(H + (size_t)s1.w * 64 + coff);
        a0 += __uint_as_float(v0.x << 16) + __uint_as_float(v1.x << 16)
            + __uint_as_float(v2.x << 16) + __uint_as_float(v3.x << 16)
            + __uint_as_float(v4.x << 16) + __uint_as_float(v5.x << 16)
            + __uint_as_float(v6.x << 16) + __uint_as_float(v7.x << 16);
        a1 += __uint_as_float(v0.x & 0xffff0000u) + __uint_as_float(v1.x & 0xffff0000u)
            + __uint_as_float(v2.x & 0xffff0000u) + __uint_as_float(v3.x & 0xffff0000u)
            + __uint_as_float(v4.x & 0xffff0000u) + __uint_as_float(v5.x & 0xffff0000u)
            + __uint_as_float(v6.x & 0xffff0000u) + __uint_as_float(v7.x & 0xffff0000u);
        a2 += __uint_as_float(v0.y << 16) + __uint_as_float(v1.y << 16)
            + __uint_as_float(v2.y << 16) + __uint_as_float(v3.y << 16)
            + __uint_as_float(v4.y << 16) + __uint_as_float(v5.y << 16)
            + __uint_as_float(v6.y << 16) + __uint_as_float(v7.y << 16);
        a3 += __uint_as_float(v0.y & 0xffff0000u) + __uint_as_float(v1.y & 0xffff0000u)
            + __uint_as_float(v2.y & 0xffff0000u) + __uint_as_float(v3.y & 0xffff0000u)
            + __uint_as_float(v4.y & 0xffff0000u) + __uint_as_float(v5.y & 0xffff0000u)
            + __uint_as_float(v6.y & 0xffff0000u) + __uint_as_float(v7.y & 0xffff0000u);
    }
    if (i + 16 <= e) {
        int4 sv = *(const int4*)(edges + i + g * 4);
        uint2 v0 = *(const uint2*)(H + (size_t)sv.x * 64 + coff);
        uint2 v1 = *(const uint2*)(H + (size_t)sv.y * 64 + coff);
        uint2 v2 = *(const uint2*)(H + (size_t)sv.z * 64 + coff);
        uint2 v3 = *(const uint2*)(H + (size_t)sv.w * 64 + coff);
        a0 += __uint_as_float(v0.x << 16) + __uint_as_float(v1.x << 16)
            + __uint_as_float(v2.x << 16) + __uint_as_float(v3.x << 16);
        a1 += __uint_as_float(v0.x & 0xffff0000u) + __uint_as_float(v1.x & 0xffff0000u)
            + __uint_as_float(v2.x & 0xffff0000u) + __uint_as_float(v3.x & 0xffff0000u);
        a2 += __uint_as_float(v0.y << 16) + __uint_as_float(v1.y << 16)
            + __uint_as_float(v2.y << 16) + __uint_as_float(v3.y << 16);
        a3 += __uint_as_float(v0.y & 0xffff0000u) + __uint_as_float(v1.y & 0xffff0000u)
            + __uint_as_float(v2.y & 0xffff0000u) + __uint_as_float(v3.y & 0xffff0000u);
        i += 16;
    }
    for (; i < e; i += 4) {             // guarded 4-edge tail
        int j = i + g;
        if (j < e) {
            uint2 v = *(const uint2*)(H + (size_t)edges[j] * 64 + coff);
            a0 += __uint_as_float(v.x << 16);
            a1 += __uint_as_float(v.x & 0xffff0000u);
            a2 += __uint_as_float(v.y << 16);
            a3 += __uint_as_float(v.y & 0xffff0000u);
        }
    }
    // butterfly: every lane gets the full edge-sum for its channel group
    a0 += __shfl_xor(a0, 16, 64); a0 += __shfl_xor(a0, 32, 64);
    a1 += __shfl_xor(a1, 16, 64); a1 += __shfl_xor(a1, 32, 64);
    a2 += __shfl_xor(a2, 16, 64); a2 += __shfl_xor(a2, 32, 64);
    a3 += __shfl_xor(a3, 16, 64); a3 += __shfl_xor(a3, 32, 64);
    // self term + bias + relu (uniform across the 4 slot-groups)
    float dv = dinv[wid];
    uint2 sv = *(const uint2*)(H + (size_t)wid * 64 + coff);   // prescaled self
    a0 += __uint_as_float(sv.x << 16);
    a1 += __uint_as_float(sv.x & 0xffff0000u);
    a2 += __uint_as_float(sv.y << 16);
    a3 += __uint_as_float(sv.y & 0xffff0000u);
    float4 bv = *(const float4*)(b1 + c4 * 4);
    float r0 = fmaxf(a0 * dv + bv.x, 0.f);
    float r1 = fmaxf(a1 * dv + bv.y, 0.f);
    float r2 = fmaxf(a2 * dv + bv.z, 0.f);
    float r3 = fmaxf(a3 * dv + bv.w, 0.f);
    // fused gemm2: out[c4] = dv * sum_k x1[k]*W2[k][c4]; lane's k-quarter = g
    float p = 0.f;
#pragma unroll
    for (int j = 0; j < 4; ++j) {
        int src = 4 * g + j;
        float x0 = __shfl(r0, src, 64);
        float x1 = __shfl(r1, src, 64);
        float x2 = __shfl(r2, src, 64);
        float x3 = __shfl(r3, src, 64);
        int kb = 16 * g + 4 * j;
        p += x0 * w2s[(kb + 0) * 17 + c4];
        p += x1 * w2s[(kb + 1) * 17 + c4];
        p += x2 * w2s[(kb + 2) * 17 + c4];
        p += x3 * w2s[(kb + 3) * 17 + c4];
    }
    p += __shfl_xor(p, 16, 64);
    p += __shfl_xor(p, 32, 64);
    if (g == 0) H2[(size_t)wid * 16 + c4] = f2bf(p * dv);
}

// ---- agg2: wave/node, 8 lanes per edge (4B each), 8 edge slots ------------
__global__ __launch_bounds__(256) void k_agg2(const unsigned short* __restrict__ H2, const int* __restrict__ edges,
                                              const int* __restrict__ start, const float* __restrict__ dinv,
                                              const float* __restrict__ b2, float* __restrict__ X2, int N) {
    int wid = blockIdx.x * 4 + (threadIdx.x >> 6);
    int lane = threadIdx.x & 63;
    if (wid >= N) return;
    int g = lane >> 3;                  // edge slot 0..7
    int c2 = lane & 7;                  // channels 2*c2, 2*c2+1
    const size_t coff = (size_t)c2 * 2;
    float a0 = 0.f, a1 = 0.f;
    int s = start[wid], e = start[wid + 1];
    int i = s;
    if ((i & 3) && i < e) {
        int lim = min(e, (i + 3) & ~3);
        int j = i + g;
        if (j < lim) {
            unsigned int v = *(const unsigned int*)(H2 + (size_t)edges[j] * 16 + coff);
            a0 += __uint_as_float(v << 16);
            a1 += __uint_as_float(v & 0xffff0000u);
        }
        i = lim;
    }
    for (; i + 64 <= e; i += 64) {      // 64 edges: 2 idx int4 + 8 gathers in flight
        int4 s0 = *(const int4*)(edges + i + g * 4);
        int4 s1 = *(const int4*)(edges + i + 32 + g * 4);
        unsigned int v0 = *(const unsigned int*)(H2 + (size_t)s0.x * 16 + coff);
        unsigned int v1 = *(const unsigned int*)(H2 + (size_t)s0.y * 16 + coff);
        unsigned int v2 = *(const unsigned int*)(H2 + (size_t)s0.z * 16 + coff);
        unsigned int v3 = *(const unsigned int*)(H2 + (size_t)s0.w * 16 + coff);
        unsigned int v4 = *(const unsigned int*)(H2 + (size_t)s1.x * 16 + coff);
        unsigned int v5 = *(const unsigned int*)(H2 + (size_t)s1.y * 16 + coff);
        unsigned int v6 = *(const unsigned int*)(H2 + (size_t)s1.z * 16 + coff);
        unsigned int v7 = *(const unsigned int*)(H2 + (size_t)s1.w * 16 + coff);
        a0 += __uint_as_float(v0 << 16) + __uint_as_float(v1 << 16)
            + __uint_as_float(v2 << 16) + __uint_as_float(v3 << 16)
            + __uint_as_float(v4 << 16) + __uint_as_float(v5 << 16)
            + __uint_as_float(v6 << 16) + __uint_as_float(v7 << 16);
        a1 += __uint_as_float(v0 & 0xffff0000u) + __uint_as_float(v1 & 0xffff0000u)
            + __uint_as_float(v2 & 0xffff0000u) + __uint_as_float(v3 & 0xffff0000u)
            + __uint_as_float(v4 & 0xffff0000u) + __uint_as_float(v5 & 0xffff0000u)
            + __uint_as_float(v6 & 0xffff0000u) + __uint_as_float(v7 & 0xffff0000u);
    }
    if (i + 32 <= e) {
        int4 sv = *(const int4*)(edges + i + g * 4);
        unsigned int v0 = *(const unsigned int*)(H2 + (size_t)sv.x * 16 + coff);
        unsigned int v1 = *(const unsigned int*)(H2 + (size_t)sv.y * 16 + coff);
        unsigned int v2 = *(const unsigned int*)(H2 + (size_t)sv.z * 16 + coff);
        unsigned int v3 = *(const unsigned int*)(H2 + (size_t)sv.w * 16 + coff);
        a0 += __uint_as_float(v0 << 16) + __uint_as_float(v1 << 16)
            + __uint_as_float(v2 << 16) + __uint_as_float(v3 << 16);
        a1 += __uint_as_float(v0 & 0xffff0000u) + __uint_as_float(v1 & 0xffff0000u)
            + __uint_as_float(v2 & 0xffff0000u) + __uint_as_float(v3 & 0xffff0000u);
        i += 32;
    }
    for (; i < e; i += 8) {             // guarded 8-edge tail
        int j = i + g;
        if (j < e) {
            unsigned int v = *(const unsigned int*)(H2 + (size_t)edges[j] * 16 + coff);
            a0 += __uint_as_float(v << 16);
            a1 += __uint_as_float(v & 0xffff0000u);
        }
    }
    a0 += __shfl_xor(a0, 8, 64); a0 += __shfl_xor(a0, 16, 64); a0 += __shfl_xor(a0, 32, 64);
    a1 += __shfl_xor(a1, 8, 64); a1 += __shfl_xor(a1, 16, 64); a1 += __shfl_xor(a1, 32, 64);
    if (g == 0) {
        float dv = dinv[wid];
        unsigned int sv = *(const unsigned int*)(H2 + (size_t)wid * 16 + coff);  // prescaled self
        a0 += __uint_as_float(sv << 16);
        a1 += __uint_as_float(sv & 0xffff0000u);
        float2 bv = *(const float2*)(b2 + c2 * 2);
        float2 o; o.x = a0 * dv + bv.x; o.y = a1 * dv + bv.y;
        *(float2*)(X2 + (size_t)wid * 16 + coff) = o;
    }
}

// ---- attention head + final linear ----------------------------------------
__global__ __launch_bounds__(256) void k_head(const float* __restrict__ X2, const float* __restrict__ G,
                                              const float* __restrict__ AW1, const float* __restrict__ AB1,
                                              const float* __restrict__ AW2, const float* __restrict__ LW,
                                              const float* __restrict__ LB, float* __restrict__ OUT, int N) {
    __shared__ float s_aw1[256], s_ab1[16], s_aw2[16], s_lw[640], s_lb[40];
    int tid = threadIdx.x;
    s_aw1[tid] = AW1[tid];
    if (tid < 16) { s_ab1[tid] = AB1[tid]; s_aw2[tid] = AW2[tid]; }
    for (int i = tid; i < 640; i += 256) s_lw[i] = LW[i];
    if (tid < 40) s_lb[tid] = LB[tid];
    __syncthreads();
    int node = blockIdx.x * 256 + tid;
    if (node >= N) return;
    float x[16], g[16];
    const float4* xp = (const float4*)(X2 + (size_t)node * 16);
    const float4* gp = (const float4*)(G + (size_t)node * 16);
#pragma unroll
    for (int q = 0; q < 4; ++q) {
        float4 v = xp[q]; x[q*4] = v.x; x[q*4+1] = v.y; x[q*4+2] = v.z; x[q*4+3] = v.w;
        float4 u = gp[q]; g[q*4] = u.x; g[q*4+1] = u.y; g[q*4+2] = u.z; g[q*4+3] = u.w;
    }
    float wx = 0.f, wg = 0.f;
#pragma unroll
    for (int j = 0; j < 16; ++j) {
        float tx = s_ab1[j], tg = s_ab1[j];
#pragma unroll
        for (int c = 0; c < 16; ++c) { tx += x[c] * s_aw1[c*16 + j]; tg += g[c] * s_aw1[c*16 + j]; }
        wx += tanhf(tx) * s_aw2[j];
        wg += tanhf(tg) * s_aw2[j];
    }
    float m = fmaxf(wx, wg);
    float ex = expf(wx - m), eg = expf(wg - m);
    float inv = 1.f / (ex + eg);
    float bx = ex * inv, bg = eg * inv;
    float emb[16];
#pragma unroll
    for (int c = 0; c < 16; ++c) emb[c] = bx * x[c] + bg * g[c];
    float* op = OUT + (size_t)node * 40;
    for (int o = 0; o < 40; ++o) {
        float a = s_lb[o];
#pragma unroll
        for (int c = 0; c < 16; ++c) a += emb[c] * s_lw[c*40 + o];
        op[o] = a;
    }
}

extern "C" void kernel_launch(void* const* d_in, const int* in_sizes, int n_in,
                              void* d_out, int out_size, void* d_ws, size_t ws_size,
                              hipStream_t stream) {
    const float* X   = (const float*)d_in[0];
    const int*   EI  = (const int*)d_in[1];
    const float* G   = (const float*)d_in[2];
    const float* W1  = (const float*)d_in[3];
    const float* B1  = (const float*)d_in[4];
    const float* W2  = (const float*)d_in[5];
    const float* B2  = (const float*)d_in[6];
    const float* AW1 = (const float*)d_in[7];
    const float* AB1 = (const float*)d_in[8];
    const float* AW2 = (const float*)d_in[9];
    const float* LW  = (const float*)d_in[10];
    const float* LB  = (const float*)d_in[11];
    float* OUT = (float*)d_out;

    const int N = in_sizes[0] / N_IN;
    const int E = in_sizes[1] / 2;
    const int NB = (N + 255) / 256;
    const int K  = NB;                 // buckets of 256 destination nodes
    const int NH = K * NBLK;           // hist entries
    const int SB = (NH + 255) / 256;   // == K (NBLK == 256)
    const int WB = (N_IN * HID + 255) / 256;   // wt blocks
    const int GB = (N + 127) / 128;            // gemm1 blocks

    char* w = (char*)d_ws;
    size_t off = 0;
    auto take = [&](size_t bytes) -> void* {
        void* p = (void*)(w + off);
        off = (off + bytes + 255) & ~(size_t)255;
        return p;
    };
    int*   hist   = (int*)take((size_t)NH * 4);
    int*   bsum   = (int*)take((size_t)SB * 4);
    int*   bexc   = (int*)take((size_t)(SB + 1) * 4);
    int*   startp = (int*)take((size_t)(N + 1) * 4);
    float* dinvp  = (float*)take((size_t)N * 4);
    int*   edges2 = (int*)take((size_t)E * 4);
    int*   edges  = (int*)take((size_t)E * 4);
    unsigned short* wt = (unsigned short*)take((size_t)N_IN * HID * 2);
    unsigned short* h1 = (unsigned short*)take((size_t)N * 64 * 2);
    unsigned short* h2 = (unsigned short*)take((size_t)N * 16 * 2);
    float* x2 = (float*)take((size_t)N * 16 * 4);
    (void)ws_size; (void)n_in; (void)out_size;

    k_histA_wt<<<NBLK + WB, 256, 0, stream>>>(EI, hist, W1, wt, E, N, K);
    k_scan_a2 <<<SB, 256, 0, stream>>>(hist, bsum, NH);
    k_scan_b  <<<1, 512, 0, stream>>>(bsum, bexc, SB);
    k_partB   <<<NBLK, 256, 0, stream>>>(EI, hist, bexc, edges2, E, N, K);
    k_gemm1   <<<GB, 256, 0, stream>>>(X, wt, h1, N);
    k_bucket  <<<K, 256, 0, stream>>>(bexc, edges2, edges, startp, dinvp, h1, N, K);
    k_agg1g2  <<<(N + 3) / 4, 256, 0, stream>>>(h1, edges, startp, dinvp, B1, W2, h2, N);
    k_agg2    <<<(N + 3) / 4, 256, 0, stream>>>(h2, edges, startp, dinvp, B2, x2, N);
    k_head    <<<NB, 256, 0, stream>>>(x2, G, AW1, AB1, AW2, LW, LB, OUT, N);
}

// Round 7
// 571.804 us; speedup vs baseline: 1.0722x; 1.0722x over previous
//
#include <hip/hip_runtime.h>

#define N_IN 512
#define HID 64
#define NBLK 256   // edge-chunk count for hist/partition passes

typedef __attribute__((ext_vector_type(4))) float f32x4;
typedef __attribute__((ext_vector_type(8))) short bf16x8;

__device__ inline float bf2f(unsigned short s) {
    union { unsigned int u; float f; } v; v.u = ((unsigned int)s) << 16; return v.f;
}
__device__ inline unsigned short f2bf(float f) {
    union { float f; unsigned int u; } v; v.f = f;
    unsigned int u = v.u;
    return (unsigned short)((u + 0x7FFFu + ((u >> 16) & 1u)) >> 16);
}

// ---- pass A: per-(bucket, chunk) histogram (LDS atomics) + W1 transpose ----
// 1024 threads/block: 16 waves/CU for latency hiding.
__global__ __launch_bounds__(1024) void k_histA_wt(const int* __restrict__ EI, int* __restrict__ hist,
                                                   const float* __restrict__ W1, unsigned short* __restrict__ Wt,
                                                   int E, int N, int K) {
    int tid = threadIdx.x;
    if (blockIdx.x >= NBLK) {   // W1 [512][64] fp32 -> Wt [64][512] bf16
        int i = (blockIdx.x - NBLK) * 1024 + tid;
        if (i < N_IN * HID) {
            int k = i >> 6, n = i & 63;
            Wt[n * 512 + k] = f2bf(W1[i]);
        }
        return;
    }
    __shared__ int hs[512];
    __shared__ int sflag;
    if (tid == 0) sflag = (EI[1] == 0 && EI[3] == 0 && EI[5] == 0 && EI[7] == 0) ? 1 : 0;
    if (tid < 512) hs[tid] = 0;
    __syncthreads();
    bool f = sflag != 0;
    int chunk = (E + NBLK - 1) / NBLK;
    int s = blockIdx.x * chunk, e = min(E, s + chunk);
    for (int i = s + tid; i < e; i += 1024) {
        int c = f ? ((const int2*)EI)[E + i].x : EI[E + i];
        if ((unsigned)c < (unsigned)N) atomicAdd(&hs[c >> 8], 1);
    }
    __syncthreads();
    for (int k = tid; k < K; k += 1024) hist[k * NBLK + blockIdx.x] = hs[k];
}

// ---- block-local exclusive scan over hist (in-place) ----
__global__ __launch_bounds__(256) void k_scan_a2(int* __restrict__ data, int* __restrict__ bsum, int n) {
    __shared__ int sd[256];
    int i = blockIdx.x * 256 + threadIdx.x;
    int v = (i < n) ? data[i] : 0;
    sd[threadIdx.x] = v;
    __syncthreads();
    for (int off = 1; off < 256; off <<= 1) {
        int t = 0;
        if (threadIdx.x >= (unsigned)off) t = sd[threadIdx.x - off];
        __syncthreads();
        sd[threadIdx.x] += t;
        __syncthreads();
    }
    if (i < n) data[i] = sd[threadIdx.x] - v;
    if (threadIdx.x == 255) bsum[blockIdx.x] = sd[255];
}

__global__ __launch_bounds__(512) void k_scan_b(const int* __restrict__ bsum, int* __restrict__ bexc, int nb) {
    __shared__ int sd[512];
    int t = threadIdx.x;
    int v = (t < nb) ? bsum[t] : 0;
    sd[t] = v;
    __syncthreads();
    for (int off = 1; off < 512; off <<= 1) {
        int u = 0;
        if (t >= off) u = sd[t - off];
        __syncthreads();
        sd[t] += u;
        __syncthreads();
    }
    if (t < nb) bexc[t] = sd[t] - v;
    if (t == 511) bexc[nb] = sd[511];
}

// ---- pass B: simple scatter, 1024 threads/block for store-queue depth ------
__global__ __launch_bounds__(1024) void k_partB(const int* __restrict__ EI, const int* __restrict__ hist,
                                                const int* __restrict__ bexc, int* __restrict__ edges2,
                                                int E, int N, int K) {
    __shared__ int cur[512];
    __shared__ int sflag;
    int tid = threadIdx.x, b = blockIdx.x;
    if (tid == 0) sflag = (EI[1] == 0 && EI[3] == 0 && EI[5] == 0 && EI[7] == 0) ? 1 : 0;
    if (tid < 512) cur[tid] = (tid < K) ? (bexc[tid] + hist[tid * NBLK + b]) : 0;
    __syncthreads();
    bool f = sflag != 0;
    int chunk = (E + NBLK - 1) / NBLK;
    int s = b * chunk, e = min(E, s + chunk);
    for (int i = s + tid; i < e; i += 1024) {
        int r, c;
        if (f) { const int2* E2 = (const int2*)EI; r = E2[i].x; c = E2[E + i].x; }
        else   { r = EI[i]; c = EI[E + i]; }
        if ((unsigned)r >= (unsigned)N || (unsigned)c >= (unsigned)N) continue;
        int pos = atomicAdd(&cur[c >> 8], 1);
        edges2[pos] = r | ((c & 255) << 20);   // r < 2^20, c_local in bits 20..27
    }
}

// ---- GEMM1 (MFMA, no LDS): H[m] = X[m]·W1 bf16 (raw; dinv applied in bucket)
__global__ __launch_bounds__(256) void k_gemm1(const float* __restrict__ X, const unsigned short* __restrict__ Wt,
                                               unsigned short* __restrict__ H, int N) {
    int tid = threadIdx.x;
    int w = tid >> 6, lane = tid & 63;
    int m_l = lane & 15, q = lane >> 4;
    int m0 = blockIdx.x * 128 + w * 32;
    int rA0 = m0 + m_l, rA1 = m0 + 16 + m_l;
    int rc0 = rA0 < N ? rA0 : N - 1;
    int rc1 = rA1 < N ? rA1 : N - 1;
    const float* baseA0 = X + (size_t)rc0 * 512 + q * 8;
    const float* baseA1 = X + (size_t)rc1 * 512 + q * 8;
    const unsigned short* baseB = Wt + (size_t)m_l * 512 + q * 8;

    f32x4 acc[2][4] = {};
#pragma unroll 4
    for (int c = 0; c < 16; ++c) {
        int ko = c * 32;
        float4 x0a = *(const float4*)(baseA0 + ko);
        float4 x0b = *(const float4*)(baseA0 + ko + 4);
        float4 x1a = *(const float4*)(baseA1 + ko);
        float4 x1b = *(const float4*)(baseA1 + ko + 4);
        bf16x8 a0, a1;
        a0[0] = (short)f2bf(x0a.x); a0[1] = (short)f2bf(x0a.y); a0[2] = (short)f2bf(x0a.z); a0[3] = (short)f2bf(x0a.w);
        a0[4] = (short)f2bf(x0b.x); a0[5] = (short)f2bf(x0b.y); a0[6] = (short)f2bf(x0b.z); a0[7] = (short)f2bf(x0b.w);
        a1[0] = (short)f2bf(x1a.x); a1[1] = (short)f2bf(x1a.y); a1[2] = (short)f2bf(x1a.z); a1[3] = (short)f2bf(x1a.w);
        a1[4] = (short)f2bf(x1b.x); a1[5] = (short)f2bf(x1b.y); a1[6] = (short)f2bf(x1b.z); a1[7] = (short)f2bf(x1b.w);
#pragma unroll
        for (int t = 0; t < 4; ++t) {
            bf16x8 bb = *(const bf16x8*)(baseB + (size_t)t * 16 * 512 + ko);
            acc[0][t] = __builtin_amdgcn_mfma_f32_16x16x32_bf16(a0, bb, acc[0][t], 0, 0, 0);
            acc[1][t] = __builtin_amdgcn_mfma_f32_16x16x32_bf16(a1, bb, acc[1][t], 0, 0, 0);
        }
    }
#pragma unroll
    for (int h = 0; h < 2; ++h) {
#pragma unroll
        for (int rg = 0; rg < 4; ++rg) {
            int row = m0 + h * 16 + q * 4 + rg;
            if (row < N) {
#pragma unroll
                for (int t = 0; t < 4; ++t)
                    H[(size_t)row * 64 + t * 16 + m_l] = f2bf(acc[h][t][rg]);
            }
        }
    }
}

// ---- per-bucket: fine CSR (start/dinv + edge scatter) + H prescale --------
__global__ __launch_bounds__(256) void k_bucket(const int* __restrict__ bexc, const int* __restrict__ edges2,
                                                int* __restrict__ edges, int* __restrict__ start,
                                                float* __restrict__ dinv, unsigned short* __restrict__ H,
                                                int N, int K) {
    __shared__ int hist[256], sd[256], cur[256];
    __shared__ float dvs[256];
    int b = blockIdx.x, tid = threadIdx.x;
    int base = bexc[b];
    int end  = bexc[b + 1];
    hist[tid] = 0;
    __syncthreads();
    for (int i = base + tid; i < end; i += 256)
        atomicAdd(&hist[(edges2[i] >> 20) & 255], 1);
    __syncthreads();
    int v = hist[tid];
    sd[tid] = v;
    __syncthreads();
    for (int off = 1; off < 256; off <<= 1) {
        int t = 0;
        if (tid >= off) t = sd[tid - off];
        __syncthreads();
        sd[tid] += t;
        __syncthreads();
    }
    int excl = sd[tid] - v;
    cur[tid] = excl;
    int node = b * 256 + tid;
    float dvv = rsqrtf((float)(v + 1));
    dvs[tid] = dvv;
    if (node < N) {
        start[node] = base + excl;
        dinv[node] = dvv;
    }
    if (b == 0 && tid == 0) start[N] = bexc[K];
    __syncthreads();
    for (int i = base + tid; i < end; i += 256) {
        int pv = edges2[i];
        int pos = atomicAdd(&cur[(pv >> 20) & 255], 1);
        edges[base + pos] = pv & 0xFFFFF;
    }
    // prescale this bucket's H rows by dinv (16 lanes per row, coalesced)
    for (int rr = tid >> 4; rr < 256; rr += 16) {
        int n2 = b * 256 + rr;
        if (n2 < N) {
            float dv2 = dvs[rr];
            uint2* pp = (uint2*)(H + (size_t)n2 * 64 + (size_t)(tid & 15) * 4);
            uint2 vv = *pp;
            float f0 = bf2f((unsigned short)(vv.x & 0xffffu)) * dv2;
            float f1 = bf2f((unsigned short)(vv.x >> 16)) * dv2;
            float f2 = bf2f((unsigned short)(vv.y & 0xffffu)) * dv2;
            float f3 = bf2f((unsigned short)(vv.y >> 16)) * dv2;
            vv.x = (unsigned int)f2bf(f0) | ((unsigned int)f2bf(f1) << 16);
            vv.y = (unsigned int)f2bf(f2) | ((unsigned int)f2bf(f3) << 16);
            *pp = vv;
        }
    }
}

// ---- fused agg1 + gemm2: wave/node; gather -> relu(x1) -> x1·W2 -> bf16 H2
__global__ __launch_bounds__(256) void k_agg1g2(const unsigned short* __restrict__ H, const int* __restrict__ edges,
                                                const int* __restrict__ start, const float* __restrict__ dinv,
                                                const float* __restrict__ b1, const float* __restrict__ W2,
                                                unsigned short* __restrict__ H2, int N) {
    __shared__ float w2s[64 * 17];   // [k][c] stride 17: 2-way bank alias only
    int tid = threadIdx.x;
    for (int i = tid; i < 1024; i += 256) { int k = i >> 4, c = i & 15; w2s[k * 17 + c] = W2[i]; }
    __syncthreads();
    int wid = blockIdx.x * 4 + (tid >> 6);
    int lane = tid & 63;
    if (wid >= N) return;
    int g = lane >> 4;                  // edge slot 0..3
    int c4 = lane & 15;                 // channel group: channels c4*4 .. +3
    const size_t coff = (size_t)c4 * 4;
    float a0 = 0.f, a1 = 0.f, a2 = 0.f, a3 = 0.f;
    int s = start[wid], e = start[wid + 1];
    int i = s;
    if ((i & 3) && i < e) {             // peel to 16B-aligned edge index
        int lim = min(e, (i + 3) & ~3);
        int j = i + g;
        if (j < lim) {
            uint2 v = *(const uint2*)(H + (size_t)edges[j] * 64 + coff);
            a0 += __uint_as_float(v.x << 16);
            a1 += __uint_as_float(v.x & 0xffff0000u);
            a2 += __uint_as_float(v.y << 16);
            a3 += __uint_as_float(v.y & 0xffff0000u);
        }
        i = lim;
    }
    for (; i + 32 <= e; i += 32) {      // 32 edges: 2 idx int4 + 8 gathers in flight
        int4 s0 = *(const int4*)(edges + i + g * 4);
        int4 s1 = *(const int4*)(edges + i + 16 + g * 4);
        uint2 v0 = *(const uint2*)(H + (size_t)s0.x * 64 + coff);
        uint2 v1 = *(const uint2*)(H + (size_t)s0.y * 64 + coff);
        uint2 v2 = *(const uint2*)(H + (size_t)s0.z * 64 + coff);
        uint2 v3 = *(const uint2*)(H + (size_t)s0.w * 64 + coff);
        uint2 v4 = *(const uint2*)(H + (size_t)s1.x * 64 + coff);
        uint2 v5 = *(const uint2*)(H + (size_t)s1.y * 64 + coff);
        uint2 v6 = *(const uint2*)(H + (size_t)s1.z * 64 + coff);
        uint2 v7 = *(const uint2*)(H + (size_t)s1.w * 64 + coff);
        a0 += __uint_as_float(v0.x << 16) + __uint_as_float(v1.x << 16)
            + __uint_as_float(v2.x << 16) + __uint_as_float(v3.x << 16)
            + __uint_as_float(v4.x << 16) + __uint_as_float(v5.x << 16)
            + __uint_as_float(v6.x << 16) + __uint_as_float(v7.x << 16);
        a1 += __uint_as_float(v0.x & 0xffff0000u) + __uint_as_float(v1.x & 0xffff0000u)
            + __uint_as_float(v2.x & 0xffff0000u) + __uint_as_float(v3.x & 0xffff0000u)
            + __uint_as_float(v4.x & 0xffff0000u) + __uint_as_float(v5.x & 0xffff0000u)
            + __uint_as_float(v6.x & 0xffff0000u) + __uint_as_float(v7.x & 0xffff0000u);
        a2 += __uint_as_float(v0.y << 16) + __uint_as_float(v1.y << 16)
            + __uint_as_float(v2.y << 16) + __uint_as_float(v3.y << 16)
            + __uint_as_float(v4.y << 16) + __uint_as_float(v5.y << 16)
            + __uint_as_float(v6.y << 16) + __uint_as_float(v7.y << 16);
        a3 += __uint_as_float(v0.y & 0xffff0000u) + __uint_as_float(v1.y & 0xffff0000u)
            + __uint_as_float(v2.y & 0xffff0000u) + __uint_as_float(v3.y & 0xffff0000u)
            + __uint_as_float(v4.y & 0xffff0000u) + __uint_as_float(v5.y & 0xffff0000u)
            + __uint_as_float(v6.y & 0xffff0000u) + __uint_as_float(v7.y & 0xffff0000u);
    }
    if (i + 16 <= e) {
        int4 sv = *(const int4*)(edges + i + g * 4);
        uint2 v0 = *(const uint2*)(H + (size_t)sv.x * 64 + coff);
        uint2 v1 = *(const uint2*)(H + (size_t)sv.y * 64 + coff);
        uint2 v2 = *(const uint2*)(H + (size_t)sv.z * 64 + coff);
        uint2 v3 = *(const uint2*)(H + (size_t)sv.w * 64 + coff);
        a0 += __uint_as_float(v0.x << 16) + __uint_as_float(v1.x << 16)
            + __uint_as_float(v2.x << 16) + __uint_as_float(v3.x << 16);
        a1 += __uint_as_float(v0.x & 0xffff0000u) + __uint_as_float(v1.x & 0xffff0000u)
            + __uint_as_float(v2.x & 0xffff0000u) + __uint_as_float(v3.x & 0xffff0000u);
        a2 += __uint_as_float(v0.y << 16) + __uint_as_float(v1.y << 16)
            + __uint_as_float(v2.y << 16) + __uint_as_float(v3.y << 16);
        a3 += __uint_as_float(v0.y & 0xffff0000u) + __uint_as_float(v1.y & 0xffff0000u)
            + __uint_as_float(v2.y & 0xffff0000u) + __uint_as_float(v3.y & 0xffff0000u);
        i += 16;
    }
    for (; i < e; i += 4) {             // guarded 4-edge tail
        int j = i + g;
        if (j < e) {
            uint2 v = *(const uint2*)(H + (size_t)edges[j] * 64 + coff);
            a0 += __uint_as_float(v.x << 16);
            a1 += __uint_as_float(v.x & 0xffff0000u);
            a2 += __uint_as_float(v.y << 16);
            a3 += __uint_as_float(v.y & 0xffff0000u);
        }
    }
    // butterfly: every lane gets the full edge-sum for its channel group
    a0 += __shfl_xor(a0, 16, 64); a0 += __shfl_xor(a0, 32, 64);
    a1 += __shfl_xor(a1, 16, 64); a1 += __shfl_xor(a1, 32, 64);
    a2 += __shfl_xor(a2, 16, 64); a2 += __shfl_xor(a2, 32, 64);
    a3 += __shfl_xor(a3, 16, 64); a3 += __shfl_xor(a3, 32, 64);
    // self term + bias + relu (uniform across the 4 slot-groups)
    float dv = dinv[wid];
    uint2 sv = *(const uint2*)(H + (size_t)wid * 64 + coff);   // prescaled self
    a0 += __uint_as_float(sv.x << 16);
    a1 += __uint_as_float(sv.x & 0xffff0000u);
    a2 += __uint_as_float(sv.y << 16);
    a3 += __uint_as_float(sv.y & 0xffff0000u);
    float4 bv = *(const float4*)(b1 + c4 * 4);
    float r0 = fmaxf(a0 * dv + bv.x, 0.f);
    float r1 = fmaxf(a1 * dv + bv.y, 0.f);
    float r2 = fmaxf(a2 * dv + bv.z, 0.f);
    float r3 = fmaxf(a3 * dv + bv.w, 0.f);
    // fused gemm2: out[c4] = dv * sum_k x1[k]*W2[k][c4]; lane's k-quarter = g
    float p = 0.f;
#pragma unroll
    for (int j = 0; j < 4; ++j) {
        int src = 4 * g + j;
        float x0 = __shfl(r0, src, 64);
        float x1 = __shfl(r1, src, 64);
        float x2 = __shfl(r2, src, 64);
        float x3 = __shfl(r3, src, 64);
        int kb = 16 * g + 4 * j;
        p += x0 * w2s[(kb + 0) * 17 + c4];
        p += x1 * w2s[(kb + 1) * 17 + c4];
        p += x2 * w2s[(kb + 2) * 17 + c4];
        p += x3 * w2s[(kb + 3) * 17 + c4];
    }
    p += __shfl_xor(p, 16, 64);
    p += __shfl_xor(p, 32, 64);
    if (g == 0) H2[(size_t)wid * 16 + c4] = f2bf(p * dv);
}

// ---- agg2: wave/node, 8 lanes per edge (4B each), 8 edge slots ------------
__global__ __launch_bounds__(256) void k_agg2(const unsigned short* __restrict__ H2, const int* __restrict__ edges,
                                              const int* __restrict__ start, const float* __restrict__ dinv,
                                              const float* __restrict__ b2, float* __restrict__ X2, int N) {
    int wid = blockIdx.x * 4 + (threadIdx.x >> 6);
    int lane = threadIdx.x & 63;
    if (wid >= N) return;
    int g = lane >> 3;                  // edge slot 0..7
    int c2 = lane & 7;                  // channels 2*c2, 2*c2+1
    const size_t coff = (size_t)c2 * 2;
    float a0 = 0.f, a1 = 0.f;
    int s = start[wid], e = start[wid + 1];
    int i = s;
    if ((i & 3) && i < e) {
        int lim = min(e, (i + 3) & ~3);
        int j = i + g;
        if (j < lim) {
            unsigned int v = *(const unsigned int*)(H2 + (size_t)edges[j] * 16 + coff);
            a0 += __uint_as_float(v << 16);
            a1 += __uint_as_float(v & 0xffff0000u);
        }
        i = lim;
    }
    for (; i + 64 <= e; i += 64) {      // 64 edges: 2 idx int4 + 8 gathers in flight
        int4 s0 = *(const int4*)(edges + i + g * 4);
        int4 s1 = *(const int4*)(edges + i + 32 + g * 4);
        unsigned int v0 = *(const unsigned int*)(H2 + (size_t)s0.x * 16 + coff);
        unsigned int v1 = *(const unsigned int*)(H2 + (size_t)s0.y * 16 + coff);
        unsigned int v2 = *(const unsigned int*)(H2 + (size_t)s0.z * 16 + coff);
        unsigned int v3 = *(const unsigned int*)(H2 + (size_t)s0.w * 16 + coff);
        unsigned int v4 = *(const unsigned int*)(H2 + (size_t)s1.x * 16 + coff);
        unsigned int v5 = *(const unsigned int*)(H2 + (size_t)s1.y * 16 + coff);
        unsigned int v6 = *(const unsigned int*)(H2 + (size_t)s1.z * 16 + coff);
        unsigned int v7 = *(const unsigned int*)(H2 + (size_t)s1.w * 16 + coff);
        a0 += __uint_as_float(v0 << 16) + __uint_as_float(v1 << 16)
            + __uint_as_float(v2 << 16) + __uint_as_float(v3 << 16)
            + __uint_as_float(v4 << 16) + __uint_as_float(v5 << 16)
            + __uint_as_float(v6 << 16) + __uint_as_float(v7 << 16);
        a1 += __uint_as_float(v0 & 0xffff0000u) + __uint_as_float(v1 & 0xffff0000u)
            + __uint_as_float(v2 & 0xffff0000u) + __uint_as_float(v3 & 0xffff0000u)
            + __uint_as_float(v4 & 0xffff0000u) + __uint_as_float(v5 & 0xffff0000u)
            + __uint_as_float(v6 & 0xffff0000u) + __uint_as_float(v7 & 0xffff0000u);
    }
    if (i + 32 <= e) {
        int4 sv = *(const int4*)(edges + i + g * 4);
        unsigned int v0 = *(const unsigned int*)(H2 + (size_t)sv.x * 16 + coff);
        unsigned int v1 = *(const unsigned int*)(H2 + (size_t)sv.y * 16 + coff);
        unsigned int v2 = *(const unsigned int*)(H2 + (size_t)sv.z * 16 + coff);
        unsigned int v3 = *(const unsigned int*)(H2 + (size_t)sv.w * 16 + coff);
        a0 += __uint_as_float(v0 << 16) + __uint_as_float(v1 << 16)
            + __uint_as_float(v2 << 16) + __uint_as_float(v3 << 16);
        a1 += __uint_as_float(v0 & 0xffff0000u) + __uint_as_float(v1 & 0xffff0000u)
            + __uint_as_float(v2 & 0xffff0000u) + __uint_as_float(v3 & 0xffff0000u);
        i += 32;
    }
    for (; i < e; i += 8) {             // guarded 8-edge tail
        int j = i + g;
        if (j < e) {
            unsigned int v = *(const unsigned int*)(H2 + (size_t)edges[j] * 16 + coff);
            a0 += __uint_as_float(v << 16);
            a1 += __uint_as_float(v & 0xffff0000u);
        }
    }
    a0 += __shfl_xor(a0, 8, 64); a0 += __shfl_xor(a0, 16, 64); a0 += __shfl_xor(a0, 32, 64);
    a1 += __shfl_xor(a1, 8, 64); a1 += __shfl_xor(a1, 16, 64); a1 += __shfl_xor(a1, 32, 64);
    if (g == 0) {
        float dv = dinv[wid];
        unsigned int sv = *(const unsigned int*)(H2 + (size_t)wid * 16 + coff);  // prescaled self
        a0 += __uint_as_float(sv << 16);
        a1 += __uint_as_float(sv & 0xffff0000u);
        float2 bv = *(const float2*)(b2 + c2 * 2);
        float2 o; o.x = a0 * dv + bv.x; o.y = a1 * dv + bv.y;
        *(float2*)(X2 + (size_t)wid * 16 + coff) = o;
    }
}

// ---- attention head + final linear ----------------------------------------
__global__ __launch_bounds__(256) void k_head(const float* __restrict__ X2, const float* __restrict__ G,
                                              const float* __restrict__ AW1, const float* __restrict__ AB1,
                                              const float* __restrict__ AW2, const float* __restrict__ LW,
                                              const float* __restrict__ LB, float* __restrict__ OUT, int N) {
    __shared__ float s_aw1[256], s_ab1[16], s_aw2[16], s_lw[640], s_lb[40];
    int tid = threadIdx.x;
    s_aw1[tid] = AW1[tid];
    if (tid < 16) { s_ab1[tid] = AB1[tid]; s_aw2[tid] = AW2[tid]; }
    for (int i = tid; i < 640; i += 256) s_lw[i] = LW[i];
    if (tid < 40) s_lb[tid] = LB[tid];
    __syncthreads();
    int node = blockIdx.x * 256 + tid;
    if (node >= N) return;
    float x[16], g[16];
    const float4* xp = (const float4*)(X2 + (size_t)node * 16);
    const float4* gp = (const float4*)(G + (size_t)node * 16);
#pragma unroll
    for (int q = 0; q < 4; ++q) {
        float4 v = xp[q]; x[q*4] = v.x; x[q*4+1] = v.y; x[q*4+2] = v.z; x[q*4+3] = v.w;
        float4 u = gp[q]; g[q*4] = u.x; g[q*4+1] = u.y; g[q*4+2] = u.z; g[q*4+3] = u.w;
    }
    float wx = 0.f, wg = 0.f;
#pragma unroll
    for (int j = 0; j < 16; ++j) {
        float tx = s_ab1[j], tg = s_ab1[j];
#pragma unroll
        for (int c = 0; c < 16; ++c) { tx += x[c] * s_aw1[c*16 + j]; tg += g[c] * s_aw1[c*16 + j]; }
        wx += tanhf(tx) * s_aw2[j];
        wg += tanhf(tg) * s_aw2[j];
    }
    float m = fmaxf(wx, wg);
    float ex = expf(wx - m), eg = expf(wg - m);
    float inv = 1.f / (ex + eg);
    float bx = ex * inv, bg = eg * inv;
    float emb[16];
#pragma unroll
    for (int c = 0; c < 16; ++c) emb[c] = bx * x[c] + bg * g[c];
    float* op = OUT + (size_t)node * 40;
    for (int o = 0; o < 40; ++o) {
        float a = s_lb[o];
#pragma unroll
        for (int c = 0; c < 16; ++c) a += emb[c] * s_lw[c*40 + o];
        op[o] = a;
    }
}

extern "C" void kernel_launch(void* const* d_in, const int* in_sizes, int n_in,
                              void* d_out, int out_size, void* d_ws, size_t ws_size,
                              hipStream_t stream) {
    const float* X   = (const float*)d_in[0];
    const int*   EI  = (const int*)d_in[1];
    const float* G   = (const float*)d_in[2];
    const float* W1  = (const float*)d_in[3];
    const float* B1  = (const float*)d_in[4];
    const float* W2  = (const float*)d_in[5];
    const float* B2  = (const float*)d_in[6];
    const float* AW1 = (const float*)d_in[7];
    const float* AB1 = (const float*)d_in[8];
    const float* AW2 = (const float*)d_in[9];
    const float* LW  = (const float*)d_in[10];
    const float* LB  = (const float*)d_in[11];
    float* OUT = (float*)d_out;

    const int N = in_sizes[0] / N_IN;
    const int E = in_sizes[1] / 2;
    const int NB = (N + 255) / 256;
    const int K  = NB;                 // buckets of 256 destination nodes
    const int NH = K * NBLK;           // hist entries
    const int SB = (NH + 255) / 256;   // scan blocks (== K when NBLK == 256)
    const int WB = (N_IN * HID + 1023) / 1024; // wt blocks (1024 thr)
    const int GB = (N + 127) / 128;            // gemm1 blocks

    char* w = (char*)d_ws;
    size_t off = 0;
    auto take = [&](size_t bytes) -> void* {
        void* p = (void*)(w + off);
        off = (off + bytes + 255) & ~(size_t)255;
        return p;
    };
    int*   hist   = (int*)take((size_t)NH * 4);
    int*   bsum   = (int*)take((size_t)SB * 4);
    int*   bexc   = (int*)take((size_t)(SB + 1) * 4);
    int*   startp = (int*)take((size_t)(N + 1) * 4);
    float* dinvp  = (float*)take((size_t)N * 4);
    int*   edges2 = (int*)take((size_t)E * 4);
    int*   edges  = (int*)take((size_t)E * 4);
    unsigned short* wt = (unsigned short*)take((size_t)N_IN * HID * 2);
    unsigned short* h1 = (unsigned short*)take((size_t)N * 64 * 2);
    unsigned short* h2 = (unsigned short*)take((size_t)N * 16 * 2);
    float* x2 = (float*)take((size_t)N * 16 * 4);
    (void)ws_size; (void)n_in; (void)out_size;

    k_histA_wt<<<NBLK + WB, 1024, 0, stream>>>(EI, hist, W1, wt, E, N, K);
    k_scan_a2 <<<SB, 256, 0, stream>>>(hist, bsum, NH);
    k_scan_b  <<<1, 512, 0, stream>>>(bsum, bexc, SB);
    k_partB   <<<NBLK, 1024, 0, stream>>>(EI, hist, bexc, edges2, E, N, K);
    k_gemm1   <<<GB, 256, 0, stream>>>(X, wt, h1, N);
    k_bucket  <<<K, 256, 0, stream>>>(bexc, edges2, edges, startp, dinvp, h1, N, K);
    k_agg1g2  <<<(N + 3) / 4, 256, 0, stream>>>(h1, edges, startp, dinvp, B1, W2, h2, N);
    k_agg2    <<<(N + 3) / 4, 256, 0, stream>>>(h2, edges, startp, dinvp, B2, x2, N);
    k_head    <<<NB, 256, 0, stream>>>(x2, G, AW1, AB1, AW2, LW, LB, OUT, N);
}